// Round 1
// baseline (448.318 us; speedup 1.0000x reference)
//
#include <hip/hip_runtime.h>

typedef __bf16 bf16x8 __attribute__((ext_vector_type(8)));
typedef float f32x4 __attribute__((ext_vector_type(4)));
typedef unsigned short ushort8 __attribute__((ext_vector_type(8)));
typedef unsigned int uint4v __attribute__((ext_vector_type(4)));
typedef unsigned int uint2v __attribute__((ext_vector_type(2)));

__device__ __forceinline__ unsigned short f2bf(float f){
    unsigned u = __float_as_uint(f);
    u += 0x7fffu + ((u >> 16) & 1u);          // RNE
    return (unsigned short)(u >> 16);
}
__device__ __forceinline__ float bflo(unsigned w){ return __uint_as_float(w << 16); }
__device__ __forceinline__ float bfhi(unsigned w){ return __uint_as_float(w & 0xffff0000u); }

#define TM 64
#define LST 136   // LDS row stride in bf16 elems: 272B, 16B-aligned, breaks row-bank aliasing

// Pack Wk/Wq/Wv (fp32 [128][128], row=k_in, col=n_out) into bf16 MFMA B-fragment
// lane order: frag b=(p*4+ks)*8+nf, lane l holds W[ks*32+(l>>4)*8+j][nf*16+(l&15)], j=0..7.
__global__ void pack_w_kernel(const float* __restrict__ Wk, const float* __restrict__ Wq,
                              const float* __restrict__ Wv, unsigned short* __restrict__ wp){
    int b = blockIdx.x;      // 0..95
    int lane = threadIdx.x;  // 0..63
    int p  = b >> 5;
    int ks = (b >> 3) & 3;
    int nf = b & 7;
    const float* W = (p == 0) ? Wk : ((p == 1) ? Wq : Wv);
    int k0  = ks * 32 + (lane >> 4) * 8;
    int col = nf * 16 + (lane & 15);
    unsigned short* dst = wp + ((size_t)b * 64 + lane) * 8;
    #pragma unroll
    for (int j = 0; j < 8; ++j) dst[j] = f2bf(W[(size_t)(k0 + j) * 128 + col]);
}

__global__ __launch_bounds__(256, 2) void fused_tcross(
        const float* __restrict__ x, const unsigned short* __restrict__ wp,
        const float* __restrict__ bk, const float* __restrict__ bq,
        const float* __restrict__ bv, float* __restrict__ out){
    __shared__ unsigned short s_x[TM][LST];        // 17408 B, x tile as bf16
    __shared__ unsigned short s_kqv[3][TM][LST];   // 52224 B, gelu'd k,q,v as bf16

    const int tid = threadIdx.x;
    const long long row0 = (long long)blockIdx.x * TM;

    // ---- stage x tile: fp32 global (coalesced float4) -> bf16 LDS ----
    const float* xblk = x + row0 * 128;
    #pragma unroll
    for (int it = 0; it < 8; ++it){
        int e = tid * 4 + it * 1024;               // 64*128 = 8192 elems
        f32x4 v = *(const f32x4*)(xblk + e);
        uint2v w;
        w[0] = (unsigned)f2bf(v[0]) | ((unsigned)f2bf(v[1]) << 16);
        w[1] = (unsigned)f2bf(v[2]) | ((unsigned)f2bf(v[3]) << 16);
        *(uint2v*)&s_x[e >> 7][e & 127] = w;
    }
    __syncthreads();

    const int lane = tid & 63;
    const int wave = tid >> 6;
    const int c16  = lane & 15;
    const int kg   = lane >> 4;

    // ---- A fragments: row=(l&15), k=(l>>4)*8+j ; reused across all 3 projections ----
    bf16x8 af[4][4];
    #pragma unroll
    for (int m = 0; m < 4; ++m)
        #pragma unroll
        for (int ks = 0; ks < 4; ++ks)
            af[m][ks] = __builtin_bit_cast(bf16x8,
                *(const ushort8*)&s_x[m * 16 + c16][ks * 32 + kg * 8]);

    // ---- 3 projections: x@W + b -> exact gelu -> bf16 LDS ----
    // waves split N: wave owns nf = 2*wave + {0,1}; each W frag reused over 4 M-frags.
    #pragma unroll 1
    for (int p = 0; p < 3; ++p){
        const float* bias = (p == 0) ? bk : ((p == 1) ? bq : bv);
        f32x4 acc[4][2];
        const f32x4 zero = {0.f, 0.f, 0.f, 0.f};
        #pragma unroll
        for (int m = 0; m < 4; ++m){ acc[m][0] = zero; acc[m][1] = zero; }
        #pragma unroll
        for (int j = 0; j < 2; ++j){
            const int nf = wave * 2 + j;
            #pragma unroll
            for (int ks = 0; ks < 4; ++ks){
                const size_t fidx = ((size_t)((p * 4 + ks) * 8 + nf) * 64 + lane) * 8;
                bf16x8 wfrag = __builtin_bit_cast(bf16x8, *(const ushort8*)(wp + fidx));
                #pragma unroll
                for (int m = 0; m < 4; ++m)
                    acc[m][j] = __builtin_amdgcn_mfma_f32_16x16x32_bf16(
                        af[m][ks], wfrag, acc[m][j], 0, 0, 0);
            }
        }
        // epilogue: C/D layout col=lane&15, row=(lane>>4)*4+i  [m89/m91]
        #pragma unroll
        for (int j = 0; j < 2; ++j){
            const int nf = wave * 2 + j;
            const float bb = bias[nf * 16 + c16];
            #pragma unroll
            for (int m = 0; m < 4; ++m){
                #pragma unroll
                for (int i = 0; i < 4; ++i){
                    float t = acc[m][j][i] + bb;
                    float g = 0.5f * t * (1.0f + erff(t * 0.70710678118f));
                    s_kqv[p][m * 16 + kg * 4 + i][nf * 16 + c16] = f2bf(g);
                }
            }
        }
    }
    __syncthreads();

    // ---- per-row einsums: 4 lanes per row, each lane owns g columns {2*sub, 2*sub+1} ----
    const int row = tid >> 2;
    const int sub = tid & 3;
    const unsigned short* krow = &s_kqv[0][row][0];
    const unsigned short* qrow = &s_kqv[1][row][0];
    float y0[8], y1[8];
    #pragma unroll
    for (int e = 0; e < 8; ++e){ y0[e] = 0.f; y1[e] = 0.f; }
    #pragma unroll
    for (int f = 0; f < 16; ++f){
        uint4v ku = *(const uint4v*)(krow + f * 8);            // k[f][0..7]
        unsigned qw = *(const unsigned*)(qrow + f * 8 + sub * 2); // q[f][g0], q[f][g0+1]
        float q0 = bflo(qw), q1 = bfhi(qw);
        float kf[8] = {bflo(ku[0]), bfhi(ku[0]), bflo(ku[1]), bfhi(ku[1]),
                       bflo(ku[2]), bfhi(ku[2]), bflo(ku[3]), bfhi(ku[3])};
        #pragma unroll
        for (int e = 0; e < 8; ++e){
            y0[e] = fmaf(kf[e], q0, y0[e]);   // y[e][g0]   += k[f][e]*q[f][g0]
            y1[e] = fmaf(kf[e], q1, y1[e]);
        }
    }
    const unsigned short* vrow = &s_kqv[2][row][0];
    const unsigned short* xr   = &s_x[row][0];
    float* outr = out + (row0 + row) * 128;
    #pragma unroll
    for (int f = 0; f < 16; ++f){
        uint4v vu = *(const uint4v*)(vrow + f * 8);            // v[f][0..7]
        float vf[8] = {bflo(vu[0]), bfhi(vu[0]), bflo(vu[1]), bfhi(vu[1]),
                       bflo(vu[2]), bfhi(vu[2]), bflo(vu[3]), bfhi(vu[3])};
        float r0 = 0.f, r1 = 0.f;
        #pragma unroll
        for (int e = 0; e < 8; ++e){
            r0 = fmaf(vf[e], y0[e], r0);      // res[f][g0] = sum_e v[f][e]*y[e][g0]
            r1 = fmaf(vf[e], y1[e], r1);
        }
        unsigned xw = *(const unsigned*)(xr + f * 8 + sub * 2);
        float2 o;
        o.x = r0 + bflo(xw);
        o.y = r1 + bfhi(xw);
        *(float2*)(outr + f * 8 + sub * 2) = o;
    }
}

extern "C" void kernel_launch(void* const* d_in, const int* in_sizes, int n_in,
                              void* d_out, int out_size, void* d_ws, size_t ws_size,
                              hipStream_t stream){
    const float* x  = (const float*)d_in[0];
    const float* Wk = (const float*)d_in[1];
    const float* bk = (const float*)d_in[2];
    const float* Wq = (const float*)d_in[3];
    const float* bq = (const float*)d_in[4];
    const float* Wv = (const float*)d_in[5];
    const float* bv = (const float*)d_in[6];
    float* out = (float*)d_out;
    unsigned short* wp = (unsigned short*)d_ws;  // needs 96 KB; ws is plenty

    const int B = in_sizes[0] / 128;             // 524288, multiple of TM=64

    pack_w_kernel<<<96, 64, 0, stream>>>(Wk, Wq, Wv, wp);
    fused_tcross<<<B / TM, 256, 0, stream>>>(x, wp, bk, bq, bv, out);

    (void)n_in; (void)out_size; (void)ws_size;
}

// Round 2
// 193.062 us; speedup vs baseline: 2.3221x; 2.3221x over previous
//
#include <hip/hip_runtime.h>

typedef __bf16 bf16x8 __attribute__((ext_vector_type(8)));
typedef float f32x4 __attribute__((ext_vector_type(4)));
typedef float f32x2 __attribute__((ext_vector_type(2)));
typedef unsigned short ushort8 __attribute__((ext_vector_type(8)));
typedef unsigned int uint4v __attribute__((ext_vector_type(4)));
typedef unsigned int uint2v __attribute__((ext_vector_type(2)));

__device__ __forceinline__ unsigned short f2bf(float f){
    unsigned u = __float_as_uint(f);
    u += 0x7fffu + ((u >> 16) & 1u);          // RNE
    return (unsigned short)(u >> 16);
}
__device__ __forceinline__ unsigned cvt_pk_bf16(float lo, float hi){
    unsigned r;
    asm("v_cvt_pk_bf16_f32 %0, %1, %2" : "=v"(r) : "v"(lo), "v"(hi));
    return r;
}
__device__ __forceinline__ float bflo(unsigned w){ return __uint_as_float(w << 16); }
__device__ __forceinline__ float bfhi(unsigned w){ return __uint_as_float(w & 0xffff0000u); }

// exact-erf gelu via Abramowitz-Stegun 7.1.26 (max |err_erf| = 1.5e-7)
__device__ __forceinline__ float gelu_fast(float x){
    float az = fabsf(x) * 0.70710678118654752f;
    float t  = __builtin_amdgcn_rcpf(fmaf(0.3275911f, az, 1.0f));
    float p  = fmaf(fmaf(fmaf(fmaf(1.061405429f, t, -1.453152027f), t,
                              1.421413741f), t, -0.284496736f), t, 0.254829592f) * t;
    float e  = __expf(-az * az);
    float h  = 0.5f * p * e;                         // = 0.5*(1 - erf(az)), in [0, 0.5]
    float phi = 0.5f + __builtin_copysignf(0.5f - h, x);
    return x * phi;
}

#define TM 64
#define LST 136   // bf16 elems per LDS row: 272B, 16B-aligned, +4-bank rotation per row

// Pack Wk/Wq/Wv (fp32 [128][128], row=k_in, col=n_out) into bf16 MFMA B-fragment
// lane order: frag b=(p*4+ks)*8+nf, lane l holds W[ks*32+(l>>4)*8+j][nf*16+(l&15)], j=0..7.
__global__ void pack_w_kernel(const float* __restrict__ Wk, const float* __restrict__ Wq,
                              const float* __restrict__ Wv, unsigned short* __restrict__ wp){
    int b = blockIdx.x;      // 0..95
    int lane = threadIdx.x;  // 0..63
    int p  = b >> 5;
    int ks = (b >> 3) & 3;
    int nf = b & 7;
    const float* W = (p == 0) ? Wk : ((p == 1) ? Wq : Wv);
    int k0  = ks * 32 + (lane >> 4) * 8;
    int col = nf * 16 + (lane & 15);
    unsigned short* dst = wp + ((size_t)b * 64 + lane) * 8;
    #pragma unroll
    for (int j = 0; j < 8; ++j) dst[j] = f2bf(W[(size_t)(k0 + j) * 128 + col]);
}

__global__ __launch_bounds__(256, 3) void fused_tcross(
        const float* __restrict__ x, const unsigned short* __restrict__ wp,
        const float* __restrict__ bk, const float* __restrict__ bq,
        const float* __restrict__ bv, float* __restrict__ out){
    // 3 planes of [TM][LST] bf16 = 52224 B total -> 3 blocks/CU.
    // plane0: x (staging + A-frags) -> k (written last) ; plane1: q ; plane2: v
    // after einsum: planes 0-1 reused as res fp32 [TM][LST]
    __shared__ __align__(16) unsigned short smem[3 * TM * LST];

    const int tid  = threadIdx.x;
    const int lane = tid & 63;
    const int wave = tid >> 6;
    const int c16  = lane & 15;
    const int kg   = lane >> 4;
    const long long row0 = (long long)blockIdx.x * TM;

    // bias prefetch: pi 0->v, 1->q, 2->k ; value at col (wave*2+j)*16 + c16
    float bpre0[2], bpre1[2], bpre2[2];
    #pragma unroll
    for (int j = 0; j < 2; ++j){
        int col = (wave * 2 + j) * 16 + c16;
        bpre0[j] = bv[col];
        bpre1[j] = bq[col];
        bpre2[j] = bk[col];
    }

    // ---- stage x tile: fp32 global -> bf16 LDS plane0; keep fp32 in regs for residual ----
    const float* xblk = x + row0 * 128;
    f32x4 resid[8];
    #pragma unroll
    for (int it = 0; it < 8; ++it){
        int e = tid * 4 + it * 1024;               // 64*128 = 8192 elems
        f32x4 v = *(const f32x4*)(xblk + e);
        resid[it] = v;
        uint2v w;
        w[0] = cvt_pk_bf16(v[0], v[1]);
        w[1] = cvt_pk_bf16(v[2], v[3]);
        *(uint2v*)&smem[(e >> 7) * LST + (e & 127)] = w;
    }
    __syncthreads();

    // ---- 3 projections (order v,q,k so plane0/x survives until the last epilogue) ----
    const int pack_p[3] = {2, 1, 0};   // wp's p index: Wv, Wq, Wk
    const int plane[3]  = {2, 1, 0};   // dest plane:   v=2, q=1, k=0
    #pragma unroll
    for (int pi = 0; pi < 3; ++pi){
        f32x4 acc[4][2];
        const f32x4 zero = {0.f, 0.f, 0.f, 0.f};
        #pragma unroll
        for (int m = 0; m < 4; ++m){ acc[m][0] = zero; acc[m][1] = zero; }
        #pragma unroll
        for (int ks = 0; ks < 4; ++ks){
            bf16x8 af[4];
            #pragma unroll
            for (int m = 0; m < 4; ++m)
                af[m] = __builtin_bit_cast(bf16x8,
                    *(const ushort8*)&smem[(m * 16 + c16) * LST + ks * 32 + kg * 8]);
            #pragma unroll
            for (int j = 0; j < 2; ++j){
                const int nf = wave * 2 + j;
                const size_t fidx = ((size_t)((pack_p[pi] * 4 + ks) * 8 + nf) * 64 + lane) * 8;
                bf16x8 wfrag = __builtin_bit_cast(bf16x8, *(const ushort8*)(wp + fidx));
                #pragma unroll
                for (int m = 0; m < 4; ++m)
                    acc[m][j] = __builtin_amdgcn_mfma_f32_16x16x32_bf16(
                        af[m], wfrag, acc[m][j], 0, 0, 0);
            }
        }
        if (pi == 2) __syncthreads();  // k overwrites plane0: wait for all A-frag reads
        unsigned short* sp = smem + plane[pi] * TM * LST;
        const float bb0 = (pi == 0) ? bpre0[0] : ((pi == 1) ? bpre1[0] : bpre2[0]);
        const float bb1 = (pi == 0) ? bpre0[1] : ((pi == 1) ? bpre1[1] : bpre2[1]);
        #pragma unroll
        for (int j = 0; j < 2; ++j){
            const int col = (wave * 2 + j) * 16 + c16;
            const float bb = j ? bb1 : bb0;
            #pragma unroll
            for (int m = 0; m < 4; ++m){
                float g0 = gelu_fast(acc[m][j][0] + bb);
                float g1 = gelu_fast(acc[m][j][1] + bb);
                float g2 = gelu_fast(acc[m][j][2] + bb);
                float g3 = gelu_fast(acc[m][j][3] + bb);
                unsigned u01 = cvt_pk_bf16(g0, g1);
                unsigned u23 = cvt_pk_bf16(g2, g3);
                const int r = m * 16 + kg * 4;
                sp[(r + 0) * LST + col] = (unsigned short)u01;
                sp[(r + 1) * LST + col] = (unsigned short)(u01 >> 16);
                sp[(r + 2) * LST + col] = (unsigned short)u23;
                sp[(r + 3) * LST + col] = (unsigned short)(u23 >> 16);
            }
        }
    }
    __syncthreads();

    // ---- per-row einsums: 4 lanes/row, lane owns g = {2*sub, 2*sub+1} ----
    const int row = tid >> 2;
    const int sub = tid & 3;
    const unsigned short* krow = smem + 0 * TM * LST + row * LST;
    const unsigned short* qrow = smem + 1 * TM * LST + row * LST;
    const unsigned short* vrow = smem + 2 * TM * LST + row * LST;

    f32x2 y2[8];
    #pragma unroll
    for (int e = 0; e < 8; ++e) y2[e] = (f32x2){0.f, 0.f};
    #pragma unroll
    for (int f = 0; f < 16; ++f){
        uint4v ku = *(const uint4v*)(krow + f * 8);                 // k[f][0..7]
        unsigned qw = *(const unsigned*)(qrow + f * 8 + sub * 2);   // q[f][g0..g0+1]
        f32x2 qq = {bflo(qw), bfhi(qw)};
        float kf[8] = {bflo(ku[0]), bfhi(ku[0]), bflo(ku[1]), bfhi(ku[1]),
                       bflo(ku[2]), bfhi(ku[2]), bflo(ku[3]), bfhi(ku[3])};
        #pragma unroll
        for (int e = 0; e < 8; ++e){
            f32x2 kk = {kf[e], kf[e]};
            y2[e] += kk * qq;                 // v_pk_fma_f32
        }
    }
    f32x2 rr[16];
    #pragma unroll
    for (int f = 0; f < 16; ++f){
        uint4v vu = *(const uint4v*)(vrow + f * 8);                 // v[f][0..7]
        float vf[8] = {bflo(vu[0]), bfhi(vu[0]), bflo(vu[1]), bfhi(vu[1]),
                       bflo(vu[2]), bfhi(vu[2]), bflo(vu[3]), bfhi(vu[3])};
        f32x2 a = {0.f, 0.f};
        #pragma unroll
        for (int e = 0; e < 8; ++e){
            f32x2 vv = {vf[e], vf[e]};
            a += vv * y2[e];
        }
        rr[f] = a;
    }
    __syncthreads();   // all k/q reads done before res overwrites planes 0-1

    float* s_res = (float*)smem;   // [TM][LST] fp32 = 34816 B over planes 0-1
    #pragma unroll
    for (int f = 0; f < 16; ++f)
        *(f32x2*)&s_res[row * LST + f * 8 + sub * 2] = rr[f];
    __syncthreads();

    // ---- coalesced store: out = res + x (residual from regs) ----
    float* outb = out + row0 * 128;
    #pragma unroll
    for (int it = 0; it < 8; ++it){
        int e = tid * 4 + it * 1024;
        f32x4 rv = *(const f32x4*)&s_res[(e >> 7) * LST + (e & 127)];
        rv += resid[it];
        *(f32x4*)(outb + e) = rv;
    }
}

extern "C" void kernel_launch(void* const* d_in, const int* in_sizes, int n_in,
                              void* d_out, int out_size, void* d_ws, size_t ws_size,
                              hipStream_t stream){
    const float* x  = (const float*)d_in[0];
    const float* Wk = (const float*)d_in[1];
    const float* bk = (const float*)d_in[2];
    const float* Wq = (const float*)d_in[3];
    const float* bq = (const float*)d_in[4];
    const float* Wv = (const float*)d_in[5];
    const float* bv = (const float*)d_in[6];
    float* out = (float*)d_out;
    unsigned short* wp = (unsigned short*)d_ws;  // 96 KB of bf16 W fragments

    const int B = in_sizes[0] / 128;             // 524288, multiple of TM=64

    pack_w_kernel<<<96, 64, 0, stream>>>(Wk, Wq, Wv, wp);
    fused_tcross<<<B / TM, 256, 0, stream>>>(x, wp, bk, bq, bv, out);

    (void)n_in; (void)out_size; (void)ws_size;
}

// Round 4
// 170.801 us; speedup vs baseline: 2.6248x; 1.1303x over previous
//
#include <hip/hip_runtime.h>

typedef __bf16 bf16x8 __attribute__((ext_vector_type(8)));
typedef float f32x4 __attribute__((ext_vector_type(4)));
typedef float f32x2 __attribute__((ext_vector_type(2)));
typedef unsigned short ushort8 __attribute__((ext_vector_type(8)));
typedef unsigned int uint4v __attribute__((ext_vector_type(4)));
typedef unsigned int uint2v __attribute__((ext_vector_type(2)));

__device__ __forceinline__ unsigned short f2bf(float f){
    unsigned u = __float_as_uint(f);
    u += 0x7fffu + ((u >> 16) & 1u);          // RNE
    return (unsigned short)(u >> 16);
}
__device__ __forceinline__ unsigned cvt_pk_bf16(float lo, float hi){
    unsigned r;
    asm("v_cvt_pk_bf16_f32 %0, %1, %2" : "=v"(r) : "v"(lo), "v"(hi));
    return r;
}
__device__ __forceinline__ float bflo(unsigned w){ return __uint_as_float(w << 16); }
__device__ __forceinline__ float bfhi(unsigned w){ return __uint_as_float(w & 0xffff0000u); }

// tanh-form gelu, ~8 VALU ops (2 transcendental). |err vs exact erf-gelu| <~ 3e-4.
__device__ __forceinline__ float gelu_tanh(float x){
    float x2 = x * x;
    float p  = fmaf(0.0356774081f, x2, 0.7978845608f);
    float t  = x * p;
    float e  = __expf(t + t);                  // e^{2u}
    float r  = __builtin_amdgcn_rcpf(e + 1.0f);
    return fmaf(-x, r, x);                     // x * (1 - 1/(1+e^{2u})) = 0.5x(1+tanh(u))
}

#define TM 64
#define LST 136   // bf16 elems per LDS row: 272B, 16B-aligned, +4-bank rotation per row

// Pack Wk/Wq/Wv (fp32 [128][128], row=k_in, col=n_out) into bf16 MFMA B-fragment
// lane order: frag b=(p*4+ks)*8+nf, lane l holds W[ks*32+(l>>4)*8+j][nf*16+(l&15)], j=0..7.
__global__ void pack_w_kernel(const float* __restrict__ Wk, const float* __restrict__ Wq,
                              const float* __restrict__ Wv, unsigned short* __restrict__ wp){
    int b = blockIdx.x;      // 0..95
    int lane = threadIdx.x;  // 0..63
    int p  = b >> 5;
    int ks = (b >> 3) & 3;
    int nf = b & 7;
    const float* W = (p == 0) ? Wk : ((p == 1) ? Wq : Wv);
    int k0  = ks * 32 + (lane >> 4) * 8;
    int col = nf * 16 + (lane & 15);
    unsigned short* dst = wp + ((size_t)b * 64 + lane) * 8;
    #pragma unroll
    for (int j = 0; j < 8; ++j) dst[j] = f2bf(W[(size_t)(k0 + j) * 128 + col]);
}

__global__ __launch_bounds__(256, 3) void fused_tcross(
        const float* __restrict__ x, const unsigned short* __restrict__ wp,
        const float* __restrict__ bk, const float* __restrict__ bq,
        const float* __restrict__ bv, float* __restrict__ out){
    // 3 planes of [TM][LST] bf16 = 52224 B total -> 3 blocks/CU.
    // plane0: x (staging + A-frags) -> k (written last) ; plane1: q ; plane2: v
    // after einsum: planes 0-1 reused as res fp32 [TM][LST]
    __shared__ __align__(16) unsigned short smem[3 * TM * LST];

    const int tid  = threadIdx.x;
    const int lane = tid & 63;
    const int wave = tid >> 6;
    const int c16  = lane & 15;
    const int kg   = lane >> 4;
    const long long row0 = (long long)blockIdx.x * TM;

    // bias prefetch: pi 0->v, 1->q, 2->k ; value at col (wave*2+j)*16 + c16
    float bpre0[2], bpre1[2], bpre2[2];
    #pragma unroll
    for (int j = 0; j < 2; ++j){
        int col = (wave * 2 + j) * 16 + c16;
        bpre0[j] = bv[col];
        bpre1[j] = bq[col];
        bpre2[j] = bk[col];
    }

    // ---- stage x tile: fp32 global -> bf16 LDS plane0; keep fp32 in regs for residual ----
    const float* xblk = x + row0 * 128;
    f32x4 resid[8];
    #pragma unroll
    for (int it = 0; it < 8; ++it){
        int e = tid * 4 + it * 1024;               // 64*128 = 8192 elems
        f32x4 v = *(const f32x4*)(xblk + e);
        resid[it] = v;
        uint2v w;
        w[0] = cvt_pk_bf16(v[0], v[1]);
        w[1] = cvt_pk_bf16(v[2], v[3]);
        *(uint2v*)&smem[(e >> 7) * LST + (e & 127)] = w;
    }
    __syncthreads();

    // ---- 3 projections (order v,q,k so plane0/x survives until the last epilogue) ----
    const int pack_p[3] = {2, 1, 0};   // wp's p index: Wv, Wq, Wk
    const int plane[3]  = {2, 1, 0};   // dest plane:   v=2, q=1, k=0
    #pragma unroll
    for (int pi = 0; pi < 3; ++pi){
        f32x4 acc[4][2];
        const f32x4 zero = {0.f, 0.f, 0.f, 0.f};
        #pragma unroll
        for (int m = 0; m < 4; ++m){ acc[m][0] = zero; acc[m][1] = zero; }
        #pragma unroll
        for (int ks = 0; ks < 4; ++ks){
            bf16x8 af[4];
            #pragma unroll
            for (int m = 0; m < 4; ++m)
                af[m] = __builtin_bit_cast(bf16x8,
                    *(const ushort8*)&smem[(m * 16 + c16) * LST + ks * 32 + kg * 8]);
            #pragma unroll
            for (int j = 0; j < 2; ++j){
                const int nf = wave * 2 + j;
                const size_t fidx = ((size_t)((pack_p[pi] * 4 + ks) * 8 + nf) * 64 + lane) * 8;
                bf16x8 wfrag = __builtin_bit_cast(bf16x8, *(const ushort8*)(wp + fidx));
                #pragma unroll
                for (int m = 0; m < 4; ++m)
                    acc[m][j] = __builtin_amdgcn_mfma_f32_16x16x32_bf16(
                        af[m], wfrag, acc[m][j], 0, 0, 0);
            }
        }
        if (pi == 2) __syncthreads();  // k overwrites plane0: wait for all A-frag reads
        unsigned short* sp = smem + plane[pi] * TM * LST;
        const float bb0 = (pi == 0) ? bpre0[0] : ((pi == 1) ? bpre1[0] : bpre2[0]);
        const float bb1 = (pi == 0) ? bpre0[1] : ((pi == 1) ? bpre1[1] : bpre2[1]);
        #pragma unroll
        for (int j = 0; j < 2; ++j){
            const int col = (wave * 2 + j) * 16 + c16;
            const float bb = j ? bb1 : bb0;
            #pragma unroll
            for (int m = 0; m < 4; ++m){
                float g0 = gelu_tanh(acc[m][j][0] + bb);
                float g1 = gelu_tanh(acc[m][j][1] + bb);
                float g2 = gelu_tanh(acc[m][j][2] + bb);
                float g3 = gelu_tanh(acc[m][j][3] + bb);
                unsigned u01 = cvt_pk_bf16(g0, g1);
                unsigned u23 = cvt_pk_bf16(g2, g3);
                const int r = m * 16 + kg * 4;
                sp[(r + 0) * LST + col] = (unsigned short)u01;
                sp[(r + 1) * LST + col] = (unsigned short)(u01 >> 16);
                sp[(r + 2) * LST + col] = (unsigned short)u23;
                sp[(r + 3) * LST + col] = (unsigned short)(u23 >> 16);
            }
        }
    }
    __syncthreads();

    // ---- per-row einsums: 4 lanes/row, lane owns g = {2*sub, 2*sub+1} ----
    const int row = tid >> 2;
    const int sub = tid & 3;
    const unsigned short* krow = smem + 0 * TM * LST + row * LST;
    const unsigned short* qrow = smem + 1 * TM * LST + row * LST;
    const unsigned short* vrow = smem + 2 * TM * LST + row * LST;

    f32x2 y2[8];
    #pragma unroll
    for (int e = 0; e < 8; ++e) y2[e] = (f32x2){0.f, 0.f};
    #pragma unroll
    for (int f = 0; f < 16; ++f){
        uint4v ku = *(const uint4v*)(krow + f * 8);                 // k[f][0..7]
        unsigned qw = *(const unsigned*)(qrow + f * 8 + sub * 2);   // q[f][g0..g0+1]
        f32x2 qq = {bflo(qw), bfhi(qw)};
        float kf[8] = {bflo(ku[0]), bfhi(ku[0]), bflo(ku[1]), bfhi(ku[1]),
                       bflo(ku[2]), bfhi(ku[2]), bflo(ku[3]), bfhi(ku[3])};
        #pragma unroll
        for (int e = 0; e < 8; ++e){
            f32x2 kk = {kf[e], kf[e]};
            y2[e] += kk * qq;                 // v_pk_fma_f32
        }
    }
    f32x2 rr[16];
    #pragma unroll
    for (int f = 0; f < 16; ++f){
        uint4v vu = *(const uint4v*)(vrow + f * 8);                 // v[f][0..7]
        float vf[8] = {bflo(vu[0]), bfhi(vu[0]), bflo(vu[1]), bfhi(vu[1]),
                       bflo(vu[2]), bfhi(vu[2]), bflo(vu[3]), bfhi(vu[3])};
        f32x2 a = {0.f, 0.f};
        #pragma unroll
        for (int e = 0; e < 8; ++e){
            f32x2 vv = {vf[e], vf[e]};
            a += vv * y2[e];
        }
        rr[f] = a;
    }
    __syncthreads();   // all k/q reads done before res overwrites planes 0-1

    float* s_res = (float*)smem;   // [TM][LST] fp32 = 34816 B over planes 0-1
    #pragma unroll
    for (int f = 0; f < 16; ++f)
        *(f32x2*)&s_res[row * LST + f * 8 + sub * 2] = rr[f];
    __syncthreads();

    // ---- coalesced store: out = res + x (residual from regs) ----
    float* outb = out + row0 * 128;
    #pragma unroll
    for (int it = 0; it < 8; ++it){
        int e = tid * 4 + it * 1024;
        f32x4 rv = *(const f32x4*)&s_res[(e >> 7) * LST + (e & 127)];
        rv += resid[it];
        *(f32x4*)(outb + e) = rv;
    }
}

extern "C" void kernel_launch(void* const* d_in, const int* in_sizes, int n_in,
                              void* d_out, int out_size, void* d_ws, size_t ws_size,
                              hipStream_t stream){
    const float* x  = (const float*)d_in[0];
    const float* Wk = (const float*)d_in[1];
    const float* bk = (const float*)d_in[2];
    const float* Wq = (const float*)d_in[3];
    const float* bq = (const float*)d_in[4];
    const float* Wv = (const float*)d_in[5];
    const float* bv = (const float*)d_in[6];
    float* out = (float*)d_out;
    unsigned short* wp = (unsigned short*)d_ws;  // 96 KB of bf16 W fragments

    const int B = in_sizes[0] / 128;             // 524288, multiple of TM=64

    pack_w_kernel<<<96, 64, 0, stream>>>(Wk, Wq, Wv, wp);
    fused_tcross<<<B / TM, 256, 0, stream>>>(x, wp, bk, bq, bv, out);

    (void)n_in; (void)out_size; (void)ws_size;
}